// Round 6
// baseline (130.880 us; speedup 1.0000x reference)
//
#include <hip/hip_runtime.h>

// ProximityAwareLoss4Class — fused weighted CE + proximity decay/boost + mean.
// B=512 rows, S=8192 positions, C=4 classes. One block per row, single kernel.
//
// TOL=5 => nearest-dist logic collapses to an 11-bit window over per-row
// bitmasks (built via wave64 ballot), plus one row-wide any_pred OR per class.
// CE values live in 8 registers across the barrier (same thread->position map
// in both passes) — no 32KB LDS staging. Final mean via last-block ticket.

#define S_LEN 8192
#define NTHREADS 1024              // 16 waves/block, 2 blocks/CU -> 32 waves/CU
#define NITER (S_LEN / NTHREADS)   // 8
#define NWORDS (S_LEN / 32)        // 256 u32 words per mask
#define NWAVES (NTHREADS / 64)     // 16

// Extract bits for positions [pos-5, pos+5] (clipped to [0,S)) into low 11 bits.
__device__ inline unsigned win11(const unsigned* m, int pos) {
    int bse = pos - 5;
    int j = bse >> 5;            // arithmetic shift; j in [-1, 255]
    int off = bse & 31;
    unsigned lo = (j >= 0) ? m[j] : 0u;
    unsigned hi = (j < NWORDS - 1) ? m[j + 1] : 0u;
    unsigned long long c = (unsigned long long)lo | ((unsigned long long)hi << 32);
    return (unsigned)((c >> off) & 0x7FFull);
}

// decay * tfac factor for one switch class.
// tw  = 11-bit window of true-switch mask (bit 5 = self)
// pw  = 11-bit window of pred-switch mask (bit 5 = self)
// anyp = any predicted switch of this class anywhere in the row
__device__ inline float prox_factor(unsigned tw, unsigned pw, bool anyp) {
    bool tm = (tw >> 5) & 1u;
    bool pm = (pw >> 5) & 1u;
    float f = 1.0f;
    unsigned tn = tw & ~(1u << 5);   // true bits excluding self
    if (pm && !tm && tn) {
        // min distance d in 1..5: bit pairs (5-d, 5+d)
        if      (tn & 0x050u) f = 0.8f;      // d=1: bits 4,6
        else if (tn & 0x088u) f = 0.64f;     // d=2: bits 3,7
        else if (tn & 0x104u) f = 0.512f;    // d=3: bits 2,8
        else if (tn & 0x202u) f = 0.4096f;   // d=4: bits 1,9
        else                  f = 0.32768f;  // d=5: bits 0,10
    }
    if (tm) {
        // d_tp <= TOL  <=>  any pred bit (incl. self) in the window
        f *= anyp ? (pw ? 1.0f : 1.5f) : 2.0f;
    }
    return f;
}

__global__ __launch_bounds__(NTHREADS)
void prox_loss_main(const float* __restrict__ logits,
                    const int* __restrict__ labels,
                    const float* __restrict__ cw,
                    float* __restrict__ acc,     // [0]=sum [1]=valid [2]=ticket(u32)
                    float* __restrict__ out,
                    int nblocks) {
    __shared__ unsigned t2m[NWORDS], t3m[NWORDS];    // 1 KB each
    __shared__ unsigned p2m[NWORDS], p3m[NWORDS];
    __shared__ unsigned anyf[2];
    __shared__ float part_s[NWAVES], part_v[NWAVES];

    const int tid = threadIdx.x;
    const long base = (long)blockIdx.x * S_LEN;

    if (tid < 2) anyf[tid] = 0u;

    const float w0 = cw[0], w1 = cw[1], w2 = cw[2], w3 = cw[3];
    const float L2E = 1.4426950408889634f;   // log2(e)
    const float LN2 = 0.6931471805599453f;   // ln(2)

    float ce_reg[NITER];
    float local_valid = 0.0f;

    // ---- Pass 1: CE per position (registers) + bitmask build ----
    for (int k = 0; k < NITER; ++k) {
        const int pos = k * NTHREADS + tid;
        const long g = base + pos;
        const float4 x = reinterpret_cast<const float4*>(logits)[g];
        const int lab = labels[g];

        // argmax (first max wins, matches jnp.argmax); best == max value
        int pred = 0; float best = x.x;
        if (x.y > best) { best = x.y; pred = 1; }
        if (x.z > best) { best = x.z; pred = 2; }
        if (x.w > best) { best = x.w; pred = 3; }

        // base-2 log-softmax: ln(sum exp(x-m)) = log2(sum 2^((x-m)*L2E)) * LN2
        const float s = exp2f((x.x - best) * L2E) + exp2f((x.y - best) * L2E)
                      + exp2f((x.z - best) * L2E) + exp2f((x.w - best) * L2E);
        const float lnsum = log2f(s) * LN2;
        const int safe = (lab < 0) ? 0 : lab;
        const float xl = (safe == 0) ? x.x : (safe == 1) ? x.y : (safe == 2) ? x.z : x.w;
        const float ws = (safe == 0) ? w0  : (safe == 1) ? w1  : (safe == 2) ? w2  : w3;
        ce_reg[k] = (lab < 0) ? 0.0f : ws * (best + lnsum - xl);
        local_valid += (lab >= 0) ? 1.0f : 0.0f;

        // wave64 ballots -> 64 consecutive positions per wave
        const unsigned long long bt2 = __ballot(lab == 2);
        const unsigned long long bt3 = __ballot(lab == 3);
        const unsigned long long bp2 = __ballot(pred == 2);
        const unsigned long long bp3 = __ballot(pred == 3);
        if ((tid & 63) == 0) {
            const int widx = pos >> 5;   // pos is a multiple of 64 here
            t2m[widx] = (unsigned)bt2; t2m[widx + 1] = (unsigned)(bt2 >> 32);
            t3m[widx] = (unsigned)bt3; t3m[widx + 1] = (unsigned)(bt3 >> 32);
            p2m[widx] = (unsigned)bp2; p2m[widx + 1] = (unsigned)(bp2 >> 32);
            p3m[widx] = (unsigned)bp3; p3m[widx + 1] = (unsigned)(bp3 >> 32);
        }
    }
    __syncthreads();

    // ---- any_pred per class (row-wide OR) ----
    if (tid < NWORDS) {
        if (p2m[tid] != 0u) atomicOr(&anyf[0], 1u);
        if (p3m[tid] != 0u) atomicOr(&anyf[1], 1u);
    }
    __syncthreads();
    const bool any2 = anyf[0] != 0u;
    const bool any3 = anyf[1] != 0u;

    // ---- Pass 2: apply proximity factors, accumulate ----
    float local_sum = 0.0f;
    for (int k = 0; k < NITER; ++k) {
        const int pos = k * NTHREADS + tid;
        float f = ce_reg[k];
        const unsigned tw2 = win11(t2m, pos), pw2 = win11(p2m, pos);
        const unsigned tw3 = win11(t3m, pos), pw3 = win11(p3m, pos);
        f *= prox_factor(tw2, pw2, any2);
        f *= prox_factor(tw3, pw3, any3);
        local_sum += f;
    }

    // ---- block reduce (wave shuffle then LDS) ----
    for (int o = 32; o > 0; o >>= 1) {
        local_sum   += __shfl_down(local_sum, o);
        local_valid += __shfl_down(local_valid, o);
    }
    const int wv = tid >> 6;
    if ((tid & 63) == 0) { part_s[wv] = local_sum; part_v[wv] = local_valid; }
    __syncthreads();

    if (tid == 0) {
        float ssum = 0.0f, vsum = 0.0f;
        for (int i = 0; i < NWAVES; ++i) { ssum += part_s[i]; vsum += part_v[i]; }
        atomicAdd(&acc[0], ssum);
        atomicAdd(&acc[1], vsum);
        __threadfence();
        const unsigned t = atomicAdd(reinterpret_cast<unsigned*>(&acc[2]), 1u);
        if (t == (unsigned)(nblocks - 1)) {
            // all other blocks' sums are visible (their fence precedes ticket)
            const float fs = atomicAdd(&acc[0], 0.0f);
            const float fv = atomicAdd(&acc[1], 0.0f);
            out[0] = fs / fmaxf(fv, 1.0f);
        }
    }
}

extern "C" void kernel_launch(void* const* d_in, const int* in_sizes, int n_in,
                              void* d_out, int out_size, void* d_ws, size_t ws_size,
                              hipStream_t stream) {
    const float* logits = (const float*)d_in[0];
    const int*   labels = (const int*)d_in[1];
    const float* cw     = (const float*)d_in[2];
    float* out = (float*)d_out;
    float* acc = (float*)d_ws;

    const int B = in_sizes[1] / S_LEN;   // 512

    hipMemsetAsync(acc, 0, 3 * sizeof(float), stream);
    prox_loss_main<<<B, NTHREADS, 0, stream>>>(logits, labels, cw, acc, out, B);
}

// Round 7
// 122.269 us; speedup vs baseline: 1.0704x; 1.0704x over previous
//
#include <hip/hip_runtime.h>

// ProximityAwareLoss4Class — fused weighted CE + proximity decay/boost + mean.
// B=512 rows, S=8192 positions, C=4 classes. One block per row, single kernel.
//
// TOL=5 => nearest-dist logic collapses to an 11-bit window over per-row
// bitmasks (built via wave64 ballot) + one row-wide any_pred OR per class.
// R7: raw v_exp/v_log builtins (no OCML wrappers), no max-subtract (|x|<~6 so
// sum 2^(x*log2e) can't overflow), direct pred==2/3 predicates (no argmax
// chain), guard-padded masks + single funnel-shift window extraction,
// depth-2 load rotation in pass 1.

#define S_LEN 8192
#define NTHREADS 1024              // 16 waves/block
#define NITER (S_LEN / NTHREADS)   // 8
#define NWORDS (S_LEN / 32)        // 256 u32 words per mask
#define NWAVES (NTHREADS / 64)     // 16

#if __has_builtin(__builtin_amdgcn_exp2f)
#define HW_EXP2(x) __builtin_amdgcn_exp2f(x)
#else
#define HW_EXP2(x) exp2f(x)
#endif
#if __has_builtin(__builtin_amdgcn_logf)
#define HW_LOG2(x) __builtin_amdgcn_logf(x)   // v_log_f32: log base 2
#else
#define HW_LOG2(x) log2f(x)
#endif

// decay * tfac factor for one switch class.
// tw = 11-bit window of true mask (bit 5 = self), pw = same for pred mask.
__device__ inline float prox_factor(unsigned tw, unsigned pw, bool anyp) {
    bool tm = (tw >> 5) & 1u;
    bool pm = (pw >> 5) & 1u;
    float f = 1.0f;
    unsigned tn = tw & ~(1u << 5);   // true bits excluding self
    if (pm && !tm && tn) {
        // min distance d in 1..5: bit pairs (5-d, 5+d)
        if      (tn & 0x050u) f = 0.8f;      // d=1: bits 4,6
        else if (tn & 0x088u) f = 0.64f;     // d=2: bits 3,7
        else if (tn & 0x104u) f = 0.512f;    // d=3: bits 2,8
        else if (tn & 0x202u) f = 0.4096f;   // d=4: bits 1,9
        else                  f = 0.32768f;  // d=5: bits 0,10
    }
    if (tm) {
        // d_tp <= TOL  <=>  any pred bit (incl. self) in the window
        f *= anyp ? (pw ? 1.0f : 1.5f) : 2.0f;
    }
    return f;
}

__device__ inline unsigned w11(unsigned lo, unsigned hi, int off) {
    unsigned long long c = (unsigned long long)lo | ((unsigned long long)hi << 32);
    return (unsigned)((c >> off) & 0x7FFull);
}

__global__ __launch_bounds__(NTHREADS)
void prox_loss_main(const float* __restrict__ logits,
                    const int* __restrict__ labels,
                    const float* __restrict__ cw,
                    float* __restrict__ acc,     // [0]=sum [1]=valid [2]=ticket(u32)
                    float* __restrict__ out,
                    int nblocks) {
    // +2 guard words (index 0 and NWORDS+1) kept at zero -> no boundary selects
    __shared__ unsigned t2g[NWORDS + 2], t3g[NWORDS + 2];
    __shared__ unsigned p2g[NWORDS + 2], p3g[NWORDS + 2];
    __shared__ unsigned anyf[2];
    __shared__ float part_s[NWAVES], part_v[NWAVES];

    const int tid = threadIdx.x;
    const long base = (long)blockIdx.x * S_LEN;
    const float4* __restrict__ lg4 = reinterpret_cast<const float4*>(logits);

    if (tid == 0) { t2g[0] = 0u; t3g[0] = 0u; p2g[0] = 0u; p3g[0] = 0u; }
    if (tid == 1) {
        t2g[NWORDS + 1] = 0u; t3g[NWORDS + 1] = 0u;
        p2g[NWORDS + 1] = 0u; p3g[NWORDS + 1] = 0u;
    }
    if (tid < 2) anyf[tid] = 0u;

    const float w0 = cw[0], w1 = cw[1], w2 = cw[2], w3 = cw[3];
    const float L2E = 1.4426950408889634f;   // log2(e)
    const float LN2 = 0.6931471805599453f;   // ln(2)

    float ce_reg[NITER];
    float local_valid = 0.0f;

    // ---- Pass 1: CE per position (registers) + bitmask build ----
    float4 xc; int lc;
    { const long g0 = base + tid; xc = lg4[g0]; lc = labels[g0]; }

#pragma unroll
    for (int k = 0; k < NITER; ++k) {
        float4 xn; int ln;
        if (k + 1 < NITER) {   // issue next-iter loads before consuming current
            const long gn = base + (long)(k + 1) * NTHREADS + tid;
            xn = lg4[gn]; ln = labels[gn];
        } else { xn = xc; ln = lc; }

        const int pos = k * NTHREADS + tid;
        const float4 x = xc; const int lab = lc;

        // first-max-wins argmax predicates (only classes 2,3 needed)
        const bool pr2 = (x.z > x.x) && (x.z > x.y) && (x.w <= x.z);
        const bool pr3 = (x.w > x.x) && (x.w > x.y) && (x.w > x.z);

        // lse without max-subtract: ln(sum e^xi) = ln2 * log2(sum 2^(xi*log2e))
        const float s = HW_EXP2(x.x * L2E) + HW_EXP2(x.y * L2E)
                      + HW_EXP2(x.z * L2E) + HW_EXP2(x.w * L2E);
        const float lse = HW_LOG2(s) * LN2;

        const int safe = (lab < 0) ? 0 : lab;
        const bool b0 = (safe & 1) != 0;
        const bool b1 = (safe & 2) != 0;
        const float xy = b0 ? x.y : x.x;
        const float zw = b0 ? x.w : x.z;
        const float xl = b1 ? zw : xy;
        const float wy = b0 ? w1 : w0;
        const float wz = b0 ? w3 : w2;
        const float ws = b1 ? wz : wy;
        ce_reg[k] = (lab < 0) ? 0.0f : ws * (lse - xl);
        local_valid += (lab >= 0) ? 1.0f : 0.0f;

        // wave64 ballots -> 64 consecutive positions per wave
        const unsigned long long bt2 = __ballot(lab == 2);
        const unsigned long long bt3 = __ballot(lab == 3);
        const unsigned long long bp2 = __ballot(pr2);
        const unsigned long long bp3 = __ballot(pr3);
        if ((tid & 63) == 0) {
            const int widx = (pos >> 5) + 1;   // +1: guard offset
            t2g[widx] = (unsigned)bt2; t2g[widx + 1] = (unsigned)(bt2 >> 32);
            t3g[widx] = (unsigned)bt3; t3g[widx + 1] = (unsigned)(bt3 >> 32);
            p2g[widx] = (unsigned)bp2; p2g[widx + 1] = (unsigned)(bp2 >> 32);
            p3g[widx] = (unsigned)bp3; p3g[widx + 1] = (unsigned)(bp3 >> 32);
        }
        xc = xn; lc = ln;
    }
    __syncthreads();

    // ---- any_pred per class (row-wide OR) ----
    if (tid < NWORDS) {
        if (p2g[tid + 1] != 0u) atomicOr(&anyf[0], 1u);
        if (p3g[tid + 1] != 0u) atomicOr(&anyf[1], 1u);
    }
    __syncthreads();
    const bool any2 = anyf[0] != 0u;
    const bool any3 = anyf[1] != 0u;

    // ---- Pass 2: apply proximity factors, accumulate ----
    float local_sum = 0.0f;
#pragma unroll
    for (int k = 0; k < NITER; ++k) {
        const int pos = k * NTHREADS + tid;
        const int bse = pos - 5;
        const int j = (bse >> 5) + 1;        // +1: guard offset; j in [0, NWORDS]
        const int off = bse & 31;
        const unsigned tw2 = w11(t2g[j], t2g[j + 1], off);
        const unsigned pw2 = w11(p2g[j], p2g[j + 1], off);
        const unsigned tw3 = w11(t3g[j], t3g[j + 1], off);
        const unsigned pw3 = w11(p3g[j], p3g[j + 1], off);
        float f = ce_reg[k];
        f *= prox_factor(tw2, pw2, any2);
        f *= prox_factor(tw3, pw3, any3);
        local_sum += f;
    }

    // ---- block reduce (wave shuffle then LDS) ----
    for (int o = 32; o > 0; o >>= 1) {
        local_sum   += __shfl_down(local_sum, o);
        local_valid += __shfl_down(local_valid, o);
    }
    const int wv = tid >> 6;
    if ((tid & 63) == 0) { part_s[wv] = local_sum; part_v[wv] = local_valid; }
    __syncthreads();

    if (tid == 0) {
        float ssum = 0.0f, vsum = 0.0f;
        for (int i = 0; i < NWAVES; ++i) { ssum += part_s[i]; vsum += part_v[i]; }
        atomicAdd(&acc[0], ssum);
        atomicAdd(&acc[1], vsum);
        __threadfence();
        const unsigned t = atomicAdd(reinterpret_cast<unsigned*>(&acc[2]), 1u);
        if (t == (unsigned)(nblocks - 1)) {
            // all other blocks' sums are visible (their fence precedes ticket)
            const float fs = atomicAdd(&acc[0], 0.0f);
            const float fv = atomicAdd(&acc[1], 0.0f);
            out[0] = fs / fmaxf(fv, 1.0f);
        }
    }
}

extern "C" void kernel_launch(void* const* d_in, const int* in_sizes, int n_in,
                              void* d_out, int out_size, void* d_ws, size_t ws_size,
                              hipStream_t stream) {
    const float* logits = (const float*)d_in[0];
    const int*   labels = (const int*)d_in[1];
    const float* cw     = (const float*)d_in[2];
    float* out = (float*)d_out;
    float* acc = (float*)d_ws;

    const int B = in_sizes[1] / S_LEN;   // 512

    hipMemsetAsync(acc, 0, 3 * sizeof(float), stream);
    prox_loss_main<<<B, NTHREADS, 0, stream>>>(logits, labels, cw, acc, out, B);
}

// Round 9
// 116.495 us; speedup vs baseline: 1.1235x; 1.0496x over previous
//
#include <hip/hip_runtime.h>

// ProximityAwareLoss4Class — fused weighted CE + proximity decay/boost + mean.
// B=512 rows, S=8192 positions, C=4 classes. One block per row + tiny finalize.
//
// TOL=5 => nearest-dist logic collapses to an 11-bit window over per-row
// bitmasks (built via wave64 ballot) + one row-wide any_pred OR per class.
// R8: two-kernel structure (no __threadfence / ticket — R6/R7's per-block
// device fence is the prime suspect for the flat 50us; R2's fence-free
// variant measured <41us). Keeps R7's cheap VALU path: raw v_exp/v_log,
// no max-subtract, predicate argmax, guard-padded funnel-shift windows.

#define S_LEN 8192
#define NTHREADS 1024              // 16 waves/block
#define NITER (S_LEN / NTHREADS)   // 8
#define NWORDS (S_LEN / 32)        // 256 u32 words per mask
#define NWAVES (NTHREADS / 64)     // 16

#if __has_builtin(__builtin_amdgcn_exp2f)
#define HW_EXP2(x) __builtin_amdgcn_exp2f(x)
#else
#define HW_EXP2(x) exp2f(x)
#endif
#if __has_builtin(__builtin_amdgcn_logf)
#define HW_LOG2(x) __builtin_amdgcn_logf(x)   // v_log_f32: log base 2
#else
#define HW_LOG2(x) log2f(x)
#endif

// decay * tfac factor for one switch class.
// tw = 11-bit window of true mask (bit 5 = self), pw = same for pred mask.
__device__ inline float prox_factor(unsigned tw, unsigned pw, bool anyp) {
    bool tm = (tw >> 5) & 1u;
    bool pm = (pw >> 5) & 1u;
    float f = 1.0f;
    unsigned tn = tw & ~(1u << 5);   // true bits excluding self
    if (pm && !tm && tn) {
        // min distance d in 1..5: bit pairs (5-d, 5+d)
        if      (tn & 0x050u) f = 0.8f;      // d=1: bits 4,6
        else if (tn & 0x088u) f = 0.64f;     // d=2: bits 3,7
        else if (tn & 0x104u) f = 0.512f;    // d=3: bits 2,8
        else if (tn & 0x202u) f = 0.4096f;   // d=4: bits 1,9
        else                  f = 0.32768f;  // d=5: bits 0,10
    }
    if (tm) {
        // d_tp <= TOL  <=>  any pred bit (incl. self) in the window
        f *= anyp ? (pw ? 1.0f : 1.5f) : 2.0f;
    }
    return f;
}

__device__ inline unsigned w11(unsigned lo, unsigned hi, int off) {
    unsigned long long c = (unsigned long long)lo | ((unsigned long long)hi << 32);
    return (unsigned)((c >> off) & 0x7FFull);
}

__global__ __launch_bounds__(NTHREADS)
void prox_loss_main(const float* __restrict__ logits,
                    const int* __restrict__ labels,
                    const float* __restrict__ cw,
                    float* __restrict__ acc) {   // [0]=sum [1]=valid
    // +2 guard words (index 0 and NWORDS+1) kept at zero -> no boundary selects
    __shared__ unsigned t2g[NWORDS + 2], t3g[NWORDS + 2];
    __shared__ unsigned p2g[NWORDS + 2], p3g[NWORDS + 2];
    __shared__ unsigned anyf[2];
    __shared__ float part_s[NWAVES], part_v[NWAVES];

    const int tid = threadIdx.x;
    const long base = (long)blockIdx.x * S_LEN;
    const float4* __restrict__ lg4 = reinterpret_cast<const float4*>(logits);

    if (tid == 0) { t2g[0] = 0u; t3g[0] = 0u; p2g[0] = 0u; p3g[0] = 0u; }
    if (tid == 1) {
        t2g[NWORDS + 1] = 0u; t3g[NWORDS + 1] = 0u;
        p2g[NWORDS + 1] = 0u; p3g[NWORDS + 1] = 0u;
    }
    if (tid < 2) anyf[tid] = 0u;

    const float w0 = cw[0], w1 = cw[1], w2 = cw[2], w3 = cw[3];
    const float L2E = 1.4426950408889634f;   // log2(e)
    const float LN2 = 0.6931471805599453f;   // ln(2)

    float ce_reg[NITER];
    float local_valid = 0.0f;

    // ---- Pass 1: CE per position (registers) + bitmask build ----
#pragma unroll
    for (int k = 0; k < NITER; ++k) {
        const int pos = k * NTHREADS + tid;
        const long g = base + pos;
        const float4 x = lg4[g];
        const int lab = labels[g];

        // first-max-wins argmax predicates (only classes 2,3 needed)
        const bool pr2 = (x.z > x.x) && (x.z > x.y) && (x.w <= x.z);
        const bool pr3 = (x.w > x.x) && (x.w > x.y) && (x.w > x.z);

        // lse without max-subtract: ln(sum e^xi) = ln2 * log2(sum 2^(xi*log2e))
        const float s = HW_EXP2(x.x * L2E) + HW_EXP2(x.y * L2E)
                      + HW_EXP2(x.z * L2E) + HW_EXP2(x.w * L2E);
        const float lse = HW_LOG2(s) * LN2;

        const int safe = (lab < 0) ? 0 : lab;
        const bool b0 = (safe & 1) != 0;
        const bool b1 = (safe & 2) != 0;
        const float xy = b0 ? x.y : x.x;
        const float zw = b0 ? x.w : x.z;
        const float xl = b1 ? zw : xy;
        const float wy = b0 ? w1 : w0;
        const float wz = b0 ? w3 : w2;
        const float ws = b1 ? wz : wy;
        ce_reg[k] = (lab < 0) ? 0.0f : ws * (lse - xl);
        local_valid += (lab >= 0) ? 1.0f : 0.0f;

        // wave64 ballots -> 64 consecutive positions per wave
        const unsigned long long bt2 = __ballot(lab == 2);
        const unsigned long long bt3 = __ballot(lab == 3);
        const unsigned long long bp2 = __ballot(pr2);
        const unsigned long long bp3 = __ballot(pr3);
        if ((tid & 63) == 0) {
            const int widx = (pos >> 5) + 1;   // +1: guard offset
            t2g[widx] = (unsigned)bt2; t2g[widx + 1] = (unsigned)(bt2 >> 32);
            t3g[widx] = (unsigned)bt3; t3g[widx + 1] = (unsigned)(bt3 >> 32);
            p2g[widx] = (unsigned)bp2; p2g[widx + 1] = (unsigned)(bp2 >> 32);
            p3g[widx] = (unsigned)bp3; p3g[widx + 1] = (unsigned)(bp3 >> 32);
        }
    }
    __syncthreads();

    // ---- any_pred per class (row-wide OR) ----
    if (tid < NWORDS) {
        if (p2g[tid + 1] != 0u) atomicOr(&anyf[0], 1u);
        if (p3g[tid + 1] != 0u) atomicOr(&anyf[1], 1u);
    }
    __syncthreads();
    const bool any2 = anyf[0] != 0u;
    const bool any3 = anyf[1] != 0u;

    // ---- Pass 2: apply proximity factors, accumulate ----
    float local_sum = 0.0f;
#pragma unroll
    for (int k = 0; k < NITER; ++k) {
        const int pos = k * NTHREADS + tid;
        const int bse = pos - 5;
        const int j = (bse >> 5) + 1;        // +1: guard offset; j in [0, NWORDS]
        const int off = bse & 31;
        const unsigned tw2 = w11(t2g[j], t2g[j + 1], off);
        const unsigned pw2 = w11(p2g[j], p2g[j + 1], off);
        const unsigned tw3 = w11(t3g[j], t3g[j + 1], off);
        const unsigned pw3 = w11(p3g[j], p3g[j + 1], off);
        float f = ce_reg[k];
        f *= prox_factor(tw2, pw2, any2);
        f *= prox_factor(tw3, pw3, any3);
        local_sum += f;
    }

    // ---- block reduce (wave shuffle then LDS) ----
    for (int o = 32; o > 0; o >>= 1) {
        local_sum   += __shfl_down(local_sum, o);
        local_valid += __shfl_down(local_valid, o);
    }
    const int wv = tid >> 6;
    if ((tid & 63) == 0) { part_s[wv] = local_sum; part_v[wv] = local_valid; }
    __syncthreads();

    if (tid == 0) {
        float ssum = 0.0f, vsum = 0.0f;
        for (int i = 0; i < NWAVES; ++i) { ssum += part_s[i]; vsum += part_v[i]; }
        atomicAdd(&acc[0], ssum);
        atomicAdd(&acc[1], vsum);
    }
}

__global__ void prox_loss_finalize(const float* __restrict__ acc,
                                   float* __restrict__ out) {
    out[0] = acc[0] / fmaxf(acc[1], 1.0f);
}

extern "C" void kernel_launch(void* const* d_in, const int* in_sizes, int n_in,
                              void* d_out, int out_size, void* d_ws, size_t ws_size,
                              hipStream_t stream) {
    const float* logits = (const float*)d_in[0];
    const int*   labels = (const int*)d_in[1];
    const float* cw     = (const float*)d_in[2];
    float* out = (float*)d_out;
    float* acc = (float*)d_ws;

    const int B = in_sizes[1] / S_LEN;   // 512

    hipMemsetAsync(acc, 0, 2 * sizeof(float), stream);
    prox_loss_main<<<B, NTHREADS, 0, stream>>>(logits, labels, cw, acc);
    prox_loss_finalize<<<1, 1, 0, stream>>>(acc, out);
}

// Round 10
// 111.677 us; speedup vs baseline: 1.1720x; 1.0431x over previous
//
#include <hip/hip_runtime.h>

// ProximityAwareLoss4Class — fused weighted CE + proximity decay/boost + mean.
// B=512 rows, S=8192, C=4. One block per row + tiny finalize. R10:
//  - 2 graph nodes (no memset): blocks write per-wave partials to unique
//    d_ws slots; finalize reduces 8192 float2.
//  - ONE __syncthreads in main (mask stores + per-wave any-flag slots before
//    it, window reads after; per-wave slots written exactly once -> no init).
//  - full register preload of 8x(float4+label) for max MLP (loads can't all
//    be in flight at VGPR=32; R9 had dropped R7's rotation).
//  - keeps: raw v_exp/v_log, no max-subtract, predicate argmax, guard-padded
//    funnel-shift 11-bit windows (TOL=5 locality), wave64 ballot masks.

#define S_LEN 8192
#define NTHREADS 1024              // 16 waves/block
#define NITER (S_LEN / NTHREADS)   // 8
#define NWORDS (S_LEN / 32)        // 256 u32 words per mask
#define NWAVES (NTHREADS / 64)     // 16

#if __has_builtin(__builtin_amdgcn_exp2f)
#define HW_EXP2(x) __builtin_amdgcn_exp2f(x)
#else
#define HW_EXP2(x) exp2f(x)
#endif
#if __has_builtin(__builtin_amdgcn_logf)
#define HW_LOG2(x) __builtin_amdgcn_logf(x)   // v_log_f32: log base 2
#else
#define HW_LOG2(x) log2f(x)
#endif

// decay * tfac factor for one switch class.
// tw = 11-bit window of true mask (bit 5 = self), pw = same for pred mask.
__device__ inline float prox_factor(unsigned tw, unsigned pw, bool anyp) {
    bool tm = (tw >> 5) & 1u;
    bool pm = (pw >> 5) & 1u;
    float f = 1.0f;
    unsigned tn = tw & ~(1u << 5);   // true bits excluding self
    if (pm && !tm && tn) {
        // min distance d in 1..5: bit pairs (5-d, 5+d)
        if      (tn & 0x050u) f = 0.8f;      // d=1: bits 4,6
        else if (tn & 0x088u) f = 0.64f;     // d=2: bits 3,7
        else if (tn & 0x104u) f = 0.512f;    // d=3: bits 2,8
        else if (tn & 0x202u) f = 0.4096f;   // d=4: bits 1,9
        else                  f = 0.32768f;  // d=5: bits 0,10
    }
    if (tm) {
        // d_tp <= TOL  <=>  any pred bit (incl. self) in the window
        f *= anyp ? (pw ? 1.0f : 1.5f) : 2.0f;
    }
    return f;
}

__device__ inline unsigned w11(unsigned lo, unsigned hi, int off) {
    unsigned long long c = (unsigned long long)lo | ((unsigned long long)hi << 32);
    return (unsigned)((c >> off) & 0x7FFull);
}

__global__ __launch_bounds__(NTHREADS)
void prox_loss_main(const float* __restrict__ logits,
                    const int* __restrict__ labels,
                    const float* __restrict__ cw,
                    float2* __restrict__ ws) {   // [B*NWAVES] per-wave partials
    // +2 guard words (index 0 and NWORDS+1) kept at zero -> no boundary selects
    __shared__ unsigned t2g[NWORDS + 2], t3g[NWORDS + 2];
    __shared__ unsigned p2g[NWORDS + 2], p3g[NWORDS + 2];
    __shared__ unsigned wany[NWAVES];   // bit0: wave saw pred==2; bit1: pred==3

    const int tid = threadIdx.x;
    const long base = (long)blockIdx.x * S_LEN;
    const float4* __restrict__ lg4 = reinterpret_cast<const float4*>(logits);

    if (tid == 0) { t2g[0] = 0u; t3g[0] = 0u; p2g[0] = 0u; p3g[0] = 0u; }
    if (tid == 1) {
        t2g[NWORDS + 1] = 0u; t3g[NWORDS + 1] = 0u;
        p2g[NWORDS + 1] = 0u; p3g[NWORDS + 1] = 0u;
    }

    const float w0 = cw[0], w1 = cw[1], w2 = cw[2], w3 = cw[3];
    const float L2E = 1.4426950408889634f;   // log2(e)
    const float LN2 = 0.6931471805599453f;   // ln(2)

    // ---- full preload: all loads issued before any consumption (max MLP) ----
    float4 x[NITER]; int lv[NITER];
#pragma unroll
    for (int k = 0; k < NITER; ++k) {
        const long g = base + (long)k * NTHREADS + tid;
        x[k] = lg4[g];
        lv[k] = labels[g];
    }

    float ce_reg[NITER];
    float local_valid = 0.0f;
    unsigned myany = 0u;

    // ---- Pass 1: CE per position (registers) + bitmask build ----
#pragma unroll
    for (int k = 0; k < NITER; ++k) {
        const int pos = k * NTHREADS + tid;
        const float4 v = x[k];
        const int lab = lv[k];

        // first-max-wins argmax predicates (only classes 2,3 needed)
        const bool pr2 = (v.z > v.x) && (v.z > v.y) && (v.w <= v.z);
        const bool pr3 = (v.w > v.x) && (v.w > v.y) && (v.w > v.z);

        // lse without max-subtract: ln(sum e^xi) = ln2 * log2(sum 2^(xi*log2e))
        const float s = HW_EXP2(v.x * L2E) + HW_EXP2(v.y * L2E)
                      + HW_EXP2(v.z * L2E) + HW_EXP2(v.w * L2E);
        const float lse = HW_LOG2(s) * LN2;

        const int safe = (lab < 0) ? 0 : lab;
        const bool b0 = (safe & 1) != 0;
        const bool b1 = (safe & 2) != 0;
        const float xy = b0 ? v.y : v.x;
        const float zw = b0 ? v.w : v.z;
        const float xl = b1 ? zw : xy;
        const float wy = b0 ? w1 : w0;
        const float wz = b0 ? w3 : w2;
        const float wsc = b1 ? wz : wy;
        ce_reg[k] = (lab < 0) ? 0.0f : wsc * (lse - xl);
        local_valid += (lab >= 0) ? 1.0f : 0.0f;

        // wave64 ballots -> 64 consecutive positions per wave
        const unsigned long long bt2 = __ballot(lab == 2);
        const unsigned long long bt3 = __ballot(lab == 3);
        const unsigned long long bp2 = __ballot(pr2);
        const unsigned long long bp3 = __ballot(pr3);
        myany |= (bp2 != 0ull ? 1u : 0u) | (bp3 != 0ull ? 2u : 0u);
        if ((tid & 63) == 0) {
            const int widx = (pos >> 5) + 1;   // +1: guard offset
            t2g[widx] = (unsigned)bt2; t2g[widx + 1] = (unsigned)(bt2 >> 32);
            t3g[widx] = (unsigned)bt3; t3g[widx + 1] = (unsigned)(bt3 >> 32);
            p2g[widx] = (unsigned)bp2; p2g[widx + 1] = (unsigned)(bp2 >> 32);
            p3g[widx] = (unsigned)bp3; p3g[widx + 1] = (unsigned)(bp3 >> 32);
        }
    }
    if ((tid & 63) == 0) wany[tid >> 6] = myany;   // each wave writes its slot

    __syncthreads();   // the ONLY barrier: masks + wany visible to all

    // ---- row-wide any_pred per class: OR of 16 per-wave flags (broadcast) ----
    unsigned aw = 0u;
#pragma unroll
    for (int i = 0; i < NWAVES; ++i) aw |= wany[i];
    const bool any2 = (aw & 1u) != 0u;
    const bool any3 = (aw & 2u) != 0u;

    // ---- Pass 2: apply proximity factors, accumulate ----
    float local_sum = 0.0f;
#pragma unroll
    for (int k = 0; k < NITER; ++k) {
        const int pos = k * NTHREADS + tid;
        const int bse = pos - 5;
        const int j = (bse >> 5) + 1;        // +1: guard offset; j in [0, NWORDS]
        const int off = bse & 31;
        const unsigned tw2 = w11(t2g[j], t2g[j + 1], off);
        const unsigned pw2 = w11(p2g[j], p2g[j + 1], off);
        const unsigned tw3 = w11(t3g[j], t3g[j + 1], off);
        const unsigned pw3 = w11(p3g[j], p3g[j + 1], off);
        float f = ce_reg[k];
        f *= prox_factor(tw2, pw2, any2);
        f *= prox_factor(tw3, pw3, any3);
        local_sum += f;
    }

    // ---- wave reduce, then one plain store per wave (no atomics, no barrier) ----
    for (int o = 32; o > 0; o >>= 1) {
        local_sum   += __shfl_down(local_sum, o);
        local_valid += __shfl_down(local_valid, o);
    }
    if ((tid & 63) == 0) {
        ws[(long)blockIdx.x * NWAVES + (tid >> 6)] =
            make_float2(local_sum, local_valid);
    }
}

__global__ __launch_bounds__(1024)
void prox_loss_finalize(const float2* __restrict__ ws,
                        float* __restrict__ out,
                        int nslots) {
    __shared__ float ps[16], pv[16];
    const int tid = threadIdx.x;
    float s = 0.0f, v = 0.0f;
    for (int i = tid; i < nslots; i += 1024) {
        const float2 t = ws[i];
        s += t.x; v += t.y;
    }
    for (int o = 32; o > 0; o >>= 1) {
        s += __shfl_down(s, o);
        v += __shfl_down(v, o);
    }
    if ((tid & 63) == 0) { ps[tid >> 6] = s; pv[tid >> 6] = v; }
    __syncthreads();
    if (tid == 0) {
        float S = 0.0f, V = 0.0f;
        for (int i = 0; i < 16; ++i) { S += ps[i]; V += pv[i]; }
        out[0] = S / fmaxf(V, 1.0f);
    }
}

extern "C" void kernel_launch(void* const* d_in, const int* in_sizes, int n_in,
                              void* d_out, int out_size, void* d_ws, size_t ws_size,
                              hipStream_t stream) {
    const float* logits = (const float*)d_in[0];
    const int*   labels = (const int*)d_in[1];
    const float* cw     = (const float*)d_in[2];
    float* out = (float*)d_out;
    float2* ws = (float2*)d_ws;

    const int B = in_sizes[1] / S_LEN;   // 512

    prox_loss_main<<<B, NTHREADS, 0, stream>>>(logits, labels, cw, ws);
    prox_loss_finalize<<<1, 1024, 0, stream>>>(ws, out, B * NWAVES);
}